// Round 3
// baseline (5751.054 us; speedup 1.0000x reference)
//
#include <hip/hip_runtime.h>

#define HID 256
typedef unsigned short bfb;  // bf16 storage (raw bits)

// ---------- bf16 bit helpers (storage-only; all math in fp32) ----------
__device__ inline float bfb2f(bfb u) {
  unsigned v = ((unsigned)u) << 16;
  float f;
  __builtin_memcpy(&f, &v, 4);
  return f;
}
__device__ inline bfb f2bfb(float f) {
  unsigned v;
  __builtin_memcpy(&v, &f, 4);
  v += 0x7fff + ((v >> 16) & 1);  // round-to-nearest-even
  return (bfb)(v >> 16);
}
__device__ inline float ldf(const float* p, size_t i) { return p[i]; }
__device__ inline float ldf(const bfb* p, size_t i) { return bfb2f(p[i]); }
__device__ inline void stf(float* p, size_t i, float v) { p[i] = v; }
__device__ inline void stf(bfb* p, size_t i, float v) { p[i] = f2bfb(v); }
__device__ inline float4 load4f(const float* p) { return *(const float4*)p; }
__device__ inline float4 load4f(const bfb* p) {
  ushort4 u = *(const ushort4*)p;
  return make_float4(bfb2f(u.x), bfb2f(u.y), bfb2f(u.z), bfb2f(u.w));
}
__device__ inline void store4f(float* p, float4 v) { *(float4*)p = v; }
__device__ inline void store4f(bfb* p, float4 v) {
  ushort4 u;
  u.x = f2bfb(v.x); u.y = f2bfb(v.y); u.z = f2bfb(v.z); u.w = f2bfb(v.w);
  *(ushort4*)p = u;
}

// ---------------- input projection: h = x @ in_W + in_b ; also z = h ----------------
template <typename TH, typename TZ>
__global__ __launch_bounds__(256) void k_input_proj(
    const float* __restrict__ x, const float* __restrict__ W,
    const float* __restrict__ bias, TH* __restrict__ h,
    TZ* __restrict__ z, int n_nodes) {
  __shared__ float sW[14 * HID];
  __shared__ float sx[64 * 14];
  for (int i = threadIdx.x; i < 14 * HID; i += blockDim.x) sW[i] = W[i];
  int c = threadIdx.x;
  float b = bias[c];
  int n0 = blockIdx.x * 64;
  int nmax = min(n0 + 64, n_nodes);
  int cnt = (nmax - n0) * 14;
  for (int i = threadIdx.x; i < cnt; i += blockDim.x) sx[i] = x[(size_t)n0 * 14 + i];
  __syncthreads();
  for (int n = n0; n < nmax; n++) {
    const float* xr = &sx[(n - n0) * 14];
    float acc = b;
#pragma unroll
    for (int k = 0; k < 14; k++) acc = fmaf(xr[k], sW[k * HID + c], acc);
    size_t idx = (size_t)n * HID + c;
    stf(h, idx, acc);
    stf(z, idx, acc);
  }
}

// ---------------- edge scatter, fp32 z: z[dst] += relu(h[src] + ea@eW + eb) ----------------
template <typename TH>
__global__ __launch_bounds__(256) void k_edge_scatter_f32(
    const float* __restrict__ ea, const int* __restrict__ eidx,
    const float* __restrict__ eW, const float* __restrict__ eb,
    const TH* __restrict__ h, float* z, int n_edges, int epb) {
  int c = threadIdx.x;
  float w0 = eW[c], w1 = eW[HID + c], w2 = eW[2 * HID + c], b = eb[c];
  const int* srcs = eidx;
  const int* dsts = eidx + n_edges;
  int e0 = blockIdx.x * epb;
  int e1 = min(e0 + epb, n_edges);
  for (int e = e0; e < e1; e++) {
    int s = srcs[e], d = dsts[e];
    float a0 = ea[(size_t)e * 3], a1 = ea[(size_t)e * 3 + 1], a2 = ea[(size_t)e * 3 + 2];
    float ec = fmaf(a0, w0, fmaf(a1, w1, fmaf(a2, w2, b)));
    float m = fmaxf(ldf(h, (size_t)s * HID + c) + ec, 0.0f);
    atomicAdd(&z[(size_t)d * HID + c], m);
  }
}

// ---------------- edge scatter, bf16 z via packed CAS ----------------
__global__ __launch_bounds__(256) void k_edge_scatter_bf(
    const float* __restrict__ ea, const int* __restrict__ eidx,
    const float* __restrict__ eW, const float* __restrict__ eb,
    const bfb* __restrict__ h, bfb* z, int n_edges, int epb) {
  int tid = threadIdx.x;
  int c2 = (tid & 127) * 2;
  int half = tid >> 7;
  float wa0 = eW[c2], wa1 = eW[c2 + 1];
  float wb0 = eW[HID + c2], wb1 = eW[HID + c2 + 1];
  float wc0 = eW[2 * HID + c2], wc1 = eW[2 * HID + c2 + 1];
  float b0 = eb[c2], b1 = eb[c2 + 1];
  const int* srcs = eidx;
  const int* dsts = eidx + n_edges;
  int e0 = blockIdx.x * epb;
  int e1 = min(e0 + epb, n_edges);
  unsigned* zw = (unsigned*)z;
  for (int e = e0 + half; e < e1; e += 2) {
    int s = srcs[e], d = dsts[e];
    float a0 = ea[(size_t)e * 3], a1 = ea[(size_t)e * 3 + 1], a2 = ea[(size_t)e * 3 + 2];
    float ec0 = fmaf(a0, wa0, fmaf(a1, wb0, fmaf(a2, wc0, b0)));
    float ec1 = fmaf(a0, wa1, fmaf(a1, wb1, fmaf(a2, wc1, b1)));
    ushort2 hv = *(const ushort2*)&h[(size_t)s * HID + c2];
    float m0 = fmaxf(bfb2f(hv.x) + ec0, 0.0f);
    float m1 = fmaxf(bfb2f(hv.y) + ec1, 0.0f);
    unsigned* addr = &zw[(size_t)d * (HID / 2) + (c2 >> 1)];
    unsigned old = *addr, assumed;
    do {
      assumed = old;
      float lo = bfb2f((bfb)(assumed & 0xffff)) + m0;
      float hi = bfb2f((bfb)(assumed >> 16)) + m1;
      unsigned nv = ((unsigned)f2bfb(hi) << 16) | (unsigned)f2bfb(lo);
      old = atomicCAS(addr, assumed, nv);
    } while (old != assumed);
  }
}

// ---------------- tiled GEMM: C[M][256] = (relu?)(A[M][256] @ W[256][256] + bias) ----------------
template <typename TA, typename TC, int RELU>
__global__ __launch_bounds__(256) void k_gemm256(
    const TA* __restrict__ A, const float* __restrict__ W,
    const float* __restrict__ bias, TC* __restrict__ C, int M) {
  __shared__ float As[16][65];
  __shared__ float Bs[16][65];
  int bm = blockIdx.x * 64;
  int bn = blockIdx.y * 64;
  int tid = threadIdx.x;
  int tx = tid & 15, ty = tid >> 4;
  float acc[4][4] = {};
  int lr = tid >> 2;
  int lk = (tid & 3) * 4;
  int wr = tid >> 4;
  int wc = (tid & 15) * 4;
  for (int k0 = 0; k0 < HID; k0 += 16) {
    float4 av = load4f(A + (size_t)(bm + lr) * HID + k0 + lk);
    As[lk + 0][lr] = av.x;
    As[lk + 1][lr] = av.y;
    As[lk + 2][lr] = av.z;
    As[lk + 3][lr] = av.w;
    float4 bv = *(const float4*)&W[(size_t)(k0 + wr) * HID + bn + wc];
    Bs[wr][wc + 0] = bv.x;
    Bs[wr][wc + 1] = bv.y;
    Bs[wr][wc + 2] = bv.z;
    Bs[wr][wc + 3] = bv.w;
    __syncthreads();
#pragma unroll
    for (int kk = 0; kk < 16; kk++) {
      float a[4], bb[4];
#pragma unroll
      for (int i = 0; i < 4; i++) a[i] = As[kk][ty * 4 + i];
#pragma unroll
      for (int j = 0; j < 4; j++) bb[j] = Bs[kk][tx * 4 + j];
#pragma unroll
      for (int i = 0; i < 4; i++)
#pragma unroll
        for (int j = 0; j < 4; j++) acc[i][j] = fmaf(a[i], bb[j], acc[i][j]);
    }
    __syncthreads();
  }
#pragma unroll
  for (int i = 0; i < 4; i++) {
    int row = bm + ty * 4 + i;
    float4 v;
    v.x = acc[i][0] + bias[bn + tx * 4 + 0];
    v.y = acc[i][1] + bias[bn + tx * 4 + 1];
    v.z = acc[i][2] + bias[bn + tx * 4 + 2];
    v.w = acc[i][3] + bias[bn + tx * 4 + 3];
    if (RELU) {
      v.x = fmaxf(v.x, 0.0f); v.y = fmaxf(v.y, 0.0f);
      v.z = fmaxf(v.z, 0.0f); v.w = fmaxf(v.w, 0.0f);
    }
    store4f(C + (size_t)row * HID + bn + tx * 4, v);
  }
}

// ---------------- BN stats ----------------
template <typename TZ>
__global__ __launch_bounds__(256) void k_bn_stats(
    const TZ* __restrict__ z, float* stats, int n_nodes) {
  int c = threadIdx.x;
  float s = 0.0f, sq = 0.0f;
  for (int n = blockIdx.x; n < n_nodes; n += gridDim.x) {
    float v = ldf(z, (size_t)n * HID + c);
    s += v;
    sq = fmaf(v, v, sq);
  }
  atomicAdd(&stats[c], s);
  atomicAdd(&stats[HID + c], sq);
}

__global__ __launch_bounds__(256) void k_bn_finalize(
    float* stats, const float* __restrict__ gamma, const float* __restrict__ beta,
    float inv_n) {
  int c = threadIdx.x;
  float mu = stats[c] * inv_n;
  float var = stats[HID + c] * inv_n - mu * mu;
  float sc = gamma[c] * rsqrtf(var + 1e-5f);
  stats[2 * HID + c] = sc;
  stats[3 * HID + c] = beta[c] - mu * sc;
}

// ---------------- BN apply + relu -> h and z ----------------
template <typename TH, typename TZ>
__global__ __launch_bounds__(256) void k_bn_apply(
    const TZ* zin, const float* __restrict__ stats,
    TH* h, TZ* z, size_t total4) {
  __shared__ float ssc[HID], ssh[HID];
  ssc[threadIdx.x] = stats[2 * HID + threadIdx.x];
  ssh[threadIdx.x] = stats[3 * HID + threadIdx.x];
  __syncthreads();
  size_t stride = (size_t)gridDim.x * blockDim.x;
  for (size_t i = (size_t)blockIdx.x * blockDim.x + threadIdx.x; i < total4; i += stride) {
    float4 v = load4f(zin + i * 4);
    int c = (int)((i * 4) & (HID - 1));
    v.x = fmaxf(fmaf(v.x, ssc[c + 0], ssh[c + 0]), 0.0f);
    v.y = fmaxf(fmaf(v.y, ssc[c + 1], ssh[c + 1]), 0.0f);
    v.z = fmaxf(fmaf(v.z, ssc[c + 2], ssh[c + 2]), 0.0f);
    v.w = fmaxf(fmaf(v.w, ssc[c + 3], ssh[c + 3]), 0.0f);
    store4f(h + i * 4, v);
    store4f(z + i * 4, v);
  }
}

// ---------------- pool ----------------
template <typename TH>
__global__ __launch_bounds__(256) void k_pool(
    const TH* __restrict__ h, const int* __restrict__ batch,
    float* out, int n_nodes, int npb) {
  int c = threadIdx.x;
  int n0 = blockIdx.x * npb;
  int n1 = min(n0 + npb, n_nodes);
  if (n0 >= n1) return;
  int cur = batch[n0];
  float acc = 0.0f;
  for (int n = n0; n < n1; n++) {
    int g = batch[n];
    if (g != cur) {
      atomicAdd(&out[(size_t)cur * HID + c], acc);
      acc = 0.0f;
      cur = g;
    }
    acc += ldf(h, (size_t)n * HID + c);
  }
  atomicAdd(&out[(size_t)cur * HID + c], acc);
}

__global__ __launch_bounds__(256) void k_div(
    float* out, const int* __restrict__ batch, int n_nodes) {
  int g = blockIdx.x;
  int lo = 0, hi = n_nodes;
  while (lo < hi) {
    int mid = (lo + hi) >> 1;
    if (batch[mid] < g) lo = mid + 1; else hi = mid;
  }
  int lo2 = lo, hi2 = n_nodes;
  while (lo2 < hi2) {
    int mid = (lo2 + hi2) >> 1;
    if (batch[mid] < g + 1) lo2 = mid + 1; else hi2 = mid;
  }
  float cnt = (float)(lo2 - lo);
  float inv = 1.0f / fmaxf(cnt, 1.0f);
  out[(size_t)g * HID + threadIdx.x] *= inv;
}

// ---------------- pipeline (templated on storage types) ----------------
template <typename TH, typename TZ>
static void run_all(const float* x, const float* edge_attr, const int* edge_index,
                    const int* batch, const float* in_W, const float* in_b,
                    const float* edge_W, const float* edge_b,
                    const float* w1, const float* b1, const float* w2, const float* b2,
                    const float* gamma, const float* beta, float* out,
                    TH* h, TZ* z, float* stats,
                    int n_nodes, int n_edges, int n_graphs, int n_layers,
                    hipStream_t stream) {
  size_t nh = (size_t)n_nodes * HID;
  k_input_proj<TH, TZ><<<(n_nodes + 63) / 64, 256, 0, stream>>>(x, in_W, in_b, h, z, n_nodes);

  for (int l = 0; l < n_layers; l++) {
    hipMemsetAsync(stats, 0, 2 * HID * sizeof(float), stream);
    if constexpr (sizeof(TZ) == 4) {
      k_edge_scatter_f32<TH><<<(n_edges + 15) / 16, 256, 0, stream>>>(
          edge_attr, edge_index, edge_W + (size_t)l * 3 * HID, edge_b + (size_t)l * HID,
          h, (float*)z, n_edges, 16);
    } else {
      k_edge_scatter_bf<<<(n_edges + 15) / 16, 256, 0, stream>>>(
          edge_attr, edge_index, edge_W + (size_t)l * 3 * HID, edge_b + (size_t)l * HID,
          (const bfb*)h, (bfb*)z, n_edges, 16);
    }
    dim3 gg((n_nodes + 63) / 64, HID / 64);
    // GEMM1: h_buf = relu(z @ w1 + b1)   (h is dead after scatter)
    k_gemm256<TZ, TH, 1><<<gg, 256, 0, stream>>>(z, w1 + (size_t)l * HID * HID,
                                                 b1 + (size_t)l * HID, h, n_nodes);
    // GEMM2: z = h_buf @ w2 + b2
    k_gemm256<TH, TZ, 0><<<gg, 256, 0, stream>>>(h, w2 + (size_t)l * HID * HID,
                                                 b2 + (size_t)l * HID, z, n_nodes);
    k_bn_stats<TZ><<<512, 256, 0, stream>>>(z, stats, n_nodes);
    k_bn_finalize<<<1, 256, 0, stream>>>(stats, gamma + (size_t)l * HID,
                                         beta + (size_t)l * HID, 1.0f / (float)n_nodes);
    k_bn_apply<TH, TZ><<<2048, 256, 0, stream>>>(z, stats, h, z, nh / 4);
  }

  k_pool<TH><<<(n_nodes + 31) / 32, 256, 0, stream>>>(h, batch, out, n_nodes, 32);
  k_div<<<n_graphs, 256, 0, stream>>>(out, batch, n_nodes);
}

extern "C" void kernel_launch(void* const* d_in, const int* in_sizes, int n_in,
                              void* d_out, int out_size, void* d_ws, size_t ws_size,
                              hipStream_t stream) {
  const float* x = (const float*)d_in[0];
  const float* edge_attr = (const float*)d_in[1];
  const int* edge_index = (const int*)d_in[2];
  const int* batch = (const int*)d_in[3];
  const float* in_W = (const float*)d_in[4];
  const float* in_b = (const float*)d_in[5];
  const float* edge_W = (const float*)d_in[6];
  const float* edge_b = (const float*)d_in[7];
  const float* w1 = (const float*)d_in[8];
  const float* b1 = (const float*)d_in[9];
  const float* w2 = (const float*)d_in[10];
  const float* b2 = (const float*)d_in[11];
  const float* gamma = (const float*)d_in[12];
  const float* beta = (const float*)d_in[13];
  float* out = (float*)d_out;

  int n_nodes = in_sizes[3];
  int n_edges = in_sizes[1] / 3;
  int n_graphs = out_size / HID;
  int n_layers = in_sizes[7] / HID;

  size_t nh = (size_t)n_nodes * HID;
  char* ws = (char*)d_ws;
  float* stats = (float*)ws;          // 4*HID f32 = 4 KB
  char* bufs = ws + 4096;
  size_t avail = ws_size > 4096 ? ws_size - 4096 : 0;

  hipMemsetAsync(out, 0, (size_t)out_size * sizeof(float), stream);

  if (avail >= nh * 8) {
    // mode 0: fp32 h + fp32 z
    float* h = (float*)bufs;
    float* z = (float*)(bufs + nh * 4);
    run_all<float, float>(x, edge_attr, edge_index, batch, in_W, in_b, edge_W, edge_b,
                          w1, b1, w2, b2, gamma, beta, out, h, z, stats,
                          n_nodes, n_edges, n_graphs, n_layers, stream);
  } else if (avail >= nh * 6) {
    // mode 1: bf16 h + fp32 z (fp32 atomics)
    bfb* h = (bfb*)bufs;
    float* z = (float*)(bufs + nh * 2);
    run_all<bfb, float>(x, edge_attr, edge_index, batch, in_W, in_b, edge_W, edge_b,
                        w1, b1, w2, b2, gamma, beta, out, h, z, stats,
                        n_nodes, n_edges, n_graphs, n_layers, stream);
  } else {
    // mode 2: bf16 h + bf16 z (packed CAS scatter-add)
    bfb* h = (bfb*)bufs;
    bfb* z = (bfb*)(bufs + nh * 2);
    run_all<bfb, bfb>(x, edge_attr, edge_index, batch, in_W, in_b, edge_W, edge_b,
                      w1, b1, w2, b2, gamma, beta, out, h, z, stats,
                      n_nodes, n_edges, n_graphs, n_layers, stream);
  }
}

// Round 4
// 2395.975 us; speedup vs baseline: 2.4003x; 2.4003x over previous
//
#include <hip/hip_runtime.h>

#define HID 256
typedef unsigned short bfb;  // bf16 storage (raw bits)
typedef __attribute__((ext_vector_type(8))) short bf16x8_t;
typedef __attribute__((ext_vector_type(4))) float f32x4_t;

// ---------- bf16 bit helpers (storage-only; math in fp32) ----------
__device__ inline float bfb2f(bfb u) {
  unsigned v = ((unsigned)u) << 16;
  float f;
  __builtin_memcpy(&f, &v, 4);
  return f;
}
__device__ inline bfb f2bfb(float f) {
  unsigned v;
  __builtin_memcpy(&v, &f, 4);
  v += 0x7fff + ((v >> 16) & 1);  // round-to-nearest-even
  return (bfb)(v >> 16);
}
__device__ inline float ldf(const bfb* p, size_t i) { return bfb2f(p[i]); }
__device__ inline void stf(bfb* p, size_t i, float v) { p[i] = f2bfb(v); }
__device__ inline float4 load4f(const bfb* p) {
  ushort4 u = *(const ushort4*)p;
  return make_float4(bfb2f(u.x), bfb2f(u.y), bfb2f(u.z), bfb2f(u.w));
}
__device__ inline void store4f(bfb* p, float4 v) {
  ushort4 u;
  u.x = f2bfb(v.x); u.y = f2bfb(v.y); u.z = f2bfb(v.z); u.w = f2bfb(v.w);
  *(ushort4*)p = u;
}

// async global->LDS, 16B per lane (dest = wave-uniform base + lane*16)
__device__ inline void gld16(const void* g, void* l) {
  __builtin_amdgcn_global_load_lds(
      (const __attribute__((address_space(1))) void*)g,
      (__attribute__((address_space(3))) void*)l, 16, 0, 0);
}

// ---------------- weight prep: Wt_hi[n][k]=bf16(W[k][n]); Wt_lo=bf16(W-hi) ----------------
__global__ __launch_bounds__(256) void k_prep_w(
    const float* __restrict__ w1, const float* __restrict__ w2,
    bfb* __restrict__ wbuf, int n_layers) {
  int t = blockIdx.x * 256 + threadIdx.x;
  int total = n_layers * 2 * 65536;
  if (t >= total) return;
  int l = t / 131072;
  int rem = t - l * 131072;
  int which = rem >> 16;   // 0 = w1, 1 = w2
  int e = rem & 65535;
  int n = e >> 8, k = e & 255;
  const float* src = (which ? w2 : w1) + (size_t)l * 65536;
  float v = src[k * 256 + n];
  bfb hi = f2bfb(v);
  bfb lo = f2bfb(v - bfb2f(hi));
  bfb* dst = wbuf + (size_t)l * 262144 + (size_t)which * 131072;
  dst[e] = hi;
  dst[65536 + e] = lo;
}

// ---------------- input projection: h = x @ in_W + in_b ; z = h ----------------
__global__ __launch_bounds__(256) void k_input_proj(
    const float* __restrict__ x, const float* __restrict__ W,
    const float* __restrict__ bias, bfb* __restrict__ h,
    bfb* __restrict__ z, int n_nodes) {
  __shared__ float sW[14 * HID];
  __shared__ float sx[64 * 14];
  for (int i = threadIdx.x; i < 14 * HID; i += blockDim.x) sW[i] = W[i];
  int c = threadIdx.x;
  float b = bias[c];
  int n0 = blockIdx.x * 64;
  int nmax = min(n0 + 64, n_nodes);
  int cnt = (nmax - n0) * 14;
  for (int i = threadIdx.x; i < cnt; i += blockDim.x) sx[i] = x[(size_t)n0 * 14 + i];
  __syncthreads();
  for (int n = n0; n < nmax; n++) {
    const float* xr = &sx[(n - n0) * 14];
    float acc = b;
#pragma unroll
    for (int k = 0; k < 14; k++) acc = fmaf(xr[k], sW[k * HID + c], acc);
    size_t idx = (size_t)n * HID + c;
    stf(h, idx, acc);
    stf(z, idx, acc);
  }
}

// ---------------- edge scatter (bf16 z via packed CAS): z[dst] += relu(h[src]+ea@eW+eb) ----------------
__global__ __launch_bounds__(256) void k_edge_scatter_bf(
    const float* __restrict__ ea, const int* __restrict__ eidx,
    const float* __restrict__ eW, const float* __restrict__ eb,
    const bfb* __restrict__ h, bfb* z, int n_edges, int epb) {
  int tid = threadIdx.x;
  int c2 = (tid & 127) * 2;
  int half = tid >> 7;
  float wa0 = eW[c2], wa1 = eW[c2 + 1];
  float wb0 = eW[HID + c2], wb1 = eW[HID + c2 + 1];
  float wc0 = eW[2 * HID + c2], wc1 = eW[2 * HID + c2 + 1];
  float b0 = eb[c2], b1 = eb[c2 + 1];
  const int* srcs = eidx;
  const int* dsts = eidx + n_edges;
  int e0 = blockIdx.x * epb;
  int e1 = min(e0 + epb, n_edges);
  unsigned* zw = (unsigned*)z;
  for (int e = e0 + half; e < e1; e += 2) {
    int s = srcs[e], d = dsts[e];
    float a0 = ea[(size_t)e * 3], a1 = ea[(size_t)e * 3 + 1], a2 = ea[(size_t)e * 3 + 2];
    float ec0 = fmaf(a0, wa0, fmaf(a1, wb0, fmaf(a2, wc0, b0)));
    float ec1 = fmaf(a0, wa1, fmaf(a1, wb1, fmaf(a2, wc1, b1)));
    ushort2 hv = *(const ushort2*)&h[(size_t)s * HID + c2];
    float m0 = fmaxf(bfb2f(hv.x) + ec0, 0.0f);
    float m1 = fmaxf(bfb2f(hv.y) + ec1, 0.0f);
    unsigned* addr = &zw[(size_t)d * (HID / 2) + (c2 >> 1)];
    unsigned old = *addr, assumed;
    do {
      assumed = old;
      float lo = bfb2f((bfb)(assumed & 0xffff)) + m0;
      float hi = bfb2f((bfb)(assumed >> 16)) + m1;
      unsigned nv = ((unsigned)f2bfb(hi) << 16) | (unsigned)f2bfb(lo);
      old = atomicCAS(addr, assumed, nv);
    } while (old != assumed);
  }
}

// ---------------- MFMA GEMM: C[Mp][256] = (relu?)(A @ (Whi+Wlo)^T' + bias), bf16 in/out ----------------
// A: [Mp][256] bf16 row-major. Whi/Wlo: [256 n][256 k] bf16 (pre-transposed).
// Tile 128x128, BK=64, 4 waves (2x2), global_load_lds + XOR-swizzled LDS.
template <int RELU>
__global__ __launch_bounds__(256) void k_gemm_mfma(
    const bfb* __restrict__ A, const bfb* __restrict__ Whi,
    const bfb* __restrict__ Wlo, const float* __restrict__ bias,
    bfb* __restrict__ C, int Mp) {
  __shared__ __align__(16) bfb As[8192];  // [128 rows][64 k] swizzled, 16KB
  __shared__ __align__(16) bfb Bh[8192];
  __shared__ __align__(16) bfb Bl[8192];
  int tid = threadIdx.x;
  int lane = tid & 63, wid = tid >> 6;
  int wr = wid >> 1, wc = wid & 1;
  size_t bm = (size_t)blockIdx.x * 128;
  int n0 = blockIdx.y * 128;

  // staging: per 4KB chunk, thread covers 16B at linear dest byte tid*16.
  // linear dest row = tid>>3, phys col byte = (tid&7)*16; logical col byte
  // is the XOR-swizzle inverse (involution) -> pre-swizzle the global source.
  int srow = tid >> 3;                                  // 0..31 within chunk
  int sel = (((tid & 7) * 16) ^ ((srow & 7) << 4)) >> 1;  // logical col elem
  int ldst = wid * 512;  // wave-uniform LDS dest offset (elems) within chunk

  f32x4_t acc[4][4] = {};

  int sw = (lane & 7) << 4;            // read-side swizzle XOR (row&7 == lane&7)
  int arow = wr * 64 + (lane & 15);    // + mi*16
  int brow = wc * 64 + (lane & 15);    // + ni*16
  int kgb = (lane >> 4) * 16;          // kbyte group within 32-k chunk

  for (int kt = 0; kt < 4; kt++) {
    int k0 = kt * 64;
    const bfb* abase = A + bm * 256 + k0 + sel;
    const bfb* hbase = Whi + (size_t)n0 * 256 + k0 + sel;
    const bfb* lbase = Wlo + (size_t)n0 * 256 + k0 + sel;
#pragma unroll
    for (int i = 0; i < 4; i++) {
      gld16(abase + (size_t)(i * 32 + srow) * 256, As + i * 2048 + ldst);
      gld16(hbase + (size_t)(i * 32 + srow) * 256, Bh + i * 2048 + ldst);
      gld16(lbase + (size_t)(i * 32 + srow) * 256, Bl + i * 2048 + ldst);
    }
    __syncthreads();
#pragma unroll
    for (int ks = 0; ks < 2; ks++) {
      int kb = ks * 64 + kgb;
      bf16x8_t af[4], bh[4], bl[4];
#pragma unroll
      for (int mi = 0; mi < 4; mi++) {
        int pb = (arow + mi * 16) * 128 + (kb ^ sw);
        af[mi] = *(const bf16x8_t*)((const char*)As + pb);
      }
#pragma unroll
      for (int ni = 0; ni < 4; ni++) {
        int pb = (brow + ni * 16) * 128 + (kb ^ sw);
        bh[ni] = *(const bf16x8_t*)((const char*)Bh + pb);
        bl[ni] = *(const bf16x8_t*)((const char*)Bl + pb);
      }
#pragma unroll
      for (int mi = 0; mi < 4; mi++)
#pragma unroll
        for (int ni = 0; ni < 4; ni++) {
          acc[mi][ni] = __builtin_amdgcn_mfma_f32_16x16x32_bf16(
              af[mi], bh[ni], acc[mi][ni], 0, 0, 0);
          acc[mi][ni] = __builtin_amdgcn_mfma_f32_16x16x32_bf16(
              af[mi], bl[ni], acc[mi][ni], 0, 0, 0);
        }
    }
    __syncthreads();
  }
  // epilogue: C/D layout col=lane&15, row=(lane>>4)*4+reg
  int crow0 = wr * 64 + (lane >> 4) * 4;
  int ccol0 = n0 + wc * 64 + (lane & 15);
#pragma unroll
  for (int ni = 0; ni < 4; ni++) {
    float b = bias[ccol0 + ni * 16];
#pragma unroll
    for (int mi = 0; mi < 4; mi++) {
#pragma unroll
      for (int r = 0; r < 4; r++) {
        float v = acc[mi][ni][r] + b;
        if (RELU) v = fmaxf(v, 0.0f);
        C[(bm + crow0 + mi * 16 + r) * 256 + ccol0 + ni * 16] = f2bfb(v);
      }
    }
  }
}

// ---------------- BN stats ----------------
__global__ __launch_bounds__(256) void k_bn_stats(
    const bfb* __restrict__ z, float* stats, int n_nodes) {
  int c = threadIdx.x;
  float s = 0.0f, sq = 0.0f;
  for (int n = blockIdx.x; n < n_nodes; n += gridDim.x) {
    float v = ldf(z, (size_t)n * HID + c);
    s += v;
    sq = fmaf(v, v, sq);
  }
  atomicAdd(&stats[c], s);
  atomicAdd(&stats[HID + c], sq);
}

__global__ __launch_bounds__(256) void k_bn_finalize(
    float* stats, const float* __restrict__ gamma, const float* __restrict__ beta,
    float inv_n) {
  int c = threadIdx.x;
  float mu = stats[c] * inv_n;
  float var = stats[HID + c] * inv_n - mu * mu;
  float sc = gamma[c] * rsqrtf(var + 1e-5f);
  stats[2 * HID + c] = sc;
  stats[3 * HID + c] = beta[c] - mu * sc;
}

// ---------------- BN apply + relu -> h and z ----------------
__global__ __launch_bounds__(256) void k_bn_apply(
    const bfb* zin, const float* __restrict__ stats,
    bfb* h, bfb* z, size_t total4) {
  __shared__ float ssc[HID], ssh[HID];
  ssc[threadIdx.x] = stats[2 * HID + threadIdx.x];
  ssh[threadIdx.x] = stats[3 * HID + threadIdx.x];
  __syncthreads();
  size_t stride = (size_t)gridDim.x * blockDim.x;
  for (size_t i = (size_t)blockIdx.x * blockDim.x + threadIdx.x; i < total4; i += stride) {
    float4 v = load4f(zin + i * 4);
    int c = (int)((i * 4) & (HID - 1));
    v.x = fmaxf(fmaf(v.x, ssc[c + 0], ssh[c + 0]), 0.0f);
    v.y = fmaxf(fmaf(v.y, ssc[c + 1], ssh[c + 1]), 0.0f);
    v.z = fmaxf(fmaf(v.z, ssc[c + 2], ssh[c + 2]), 0.0f);
    v.w = fmaxf(fmaf(v.w, ssc[c + 3], ssh[c + 3]), 0.0f);
    store4f(h + i * 4, v);
    store4f(z + i * 4, v);
  }
}

// ---------------- pool + divide ----------------
__global__ __launch_bounds__(256) void k_pool(
    const bfb* __restrict__ h, const int* __restrict__ batch,
    float* out, int n_nodes, int npb) {
  int c = threadIdx.x;
  int n0 = blockIdx.x * npb;
  int n1 = min(n0 + npb, n_nodes);
  if (n0 >= n1) return;
  int cur = batch[n0];
  float acc = 0.0f;
  for (int n = n0; n < n1; n++) {
    int g = batch[n];
    if (g != cur) {
      atomicAdd(&out[(size_t)cur * HID + c], acc);
      acc = 0.0f;
      cur = g;
    }
    acc += ldf(h, (size_t)n * HID + c);
  }
  atomicAdd(&out[(size_t)cur * HID + c], acc);
}

__global__ __launch_bounds__(256) void k_div(
    float* out, const int* __restrict__ batch, int n_nodes) {
  int g = blockIdx.x;
  int lo = 0, hi = n_nodes;
  while (lo < hi) {
    int mid = (lo + hi) >> 1;
    if (batch[mid] < g) lo = mid + 1; else hi = mid;
  }
  int lo2 = lo, hi2 = n_nodes;
  while (lo2 < hi2) {
    int mid = (lo2 + hi2) >> 1;
    if (batch[mid] < g + 1) lo2 = mid + 1; else hi2 = mid;
  }
  float cnt = (float)(lo2 - lo);
  float inv = 1.0f / fmaxf(cnt, 1.0f);
  out[(size_t)g * HID + threadIdx.x] *= inv;
}

extern "C" void kernel_launch(void* const* d_in, const int* in_sizes, int n_in,
                              void* d_out, int out_size, void* d_ws, size_t ws_size,
                              hipStream_t stream) {
  const float* x = (const float*)d_in[0];
  const float* edge_attr = (const float*)d_in[1];
  const int* edge_index = (const int*)d_in[2];
  const int* batch = (const int*)d_in[3];
  const float* in_W = (const float*)d_in[4];
  const float* in_b = (const float*)d_in[5];
  const float* edge_W = (const float*)d_in[6];
  const float* edge_b = (const float*)d_in[7];
  const float* w1 = (const float*)d_in[8];
  const float* b1 = (const float*)d_in[9];
  const float* w2 = (const float*)d_in[10];
  const float* b2 = (const float*)d_in[11];
  const float* gamma = (const float*)d_in[12];
  const float* beta = (const float*)d_in[13];
  float* out = (float*)d_out;

  int n_nodes = in_sizes[3];
  int n_edges = in_sizes[1] / 3;
  int n_graphs = out_size / HID;
  int n_layers = in_sizes[7] / HID;

  int Mp = ((n_nodes + 127) / 128) * 128;   // pad M for 128-row tiles
  size_t nh = (size_t)n_nodes * HID;
  size_t nhp = (size_t)Mp * HID;

  // ws layout: stats(4KB) | wbuf(n_layers*512KB) | h bf16 (Mp*512B) | z bf16
  char* ws = (char*)d_ws;
  float* stats = (float*)ws;
  bfb* wbuf = (bfb*)(ws + 4096);
  bfb* h = (bfb*)(ws + 4096 + (size_t)n_layers * 262144 * 2);
  bfb* z = h + nhp;

  hipMemsetAsync(out, 0, (size_t)out_size * sizeof(float), stream);
  k_prep_w<<<(n_layers * 131072 + 255) / 256, 256, 0, stream>>>(w1, w2, wbuf, n_layers);
  k_input_proj<<<(n_nodes + 63) / 64, 256, 0, stream>>>(x, in_W, in_b, h, z, n_nodes);

  dim3 gg(Mp / 128, 2);
  for (int l = 0; l < n_layers; l++) {
    hipMemsetAsync(stats, 0, 2 * HID * sizeof(float), stream);
    k_edge_scatter_bf<<<(n_edges + 15) / 16, 256, 0, stream>>>(
        edge_attr, edge_index, edge_W + (size_t)l * 3 * HID, edge_b + (size_t)l * HID,
        h, z, n_edges, 16);
    bfb* w1hi = wbuf + (size_t)l * 262144;
    bfb* w2hi = w1hi + 131072;
    // GEMM1: h = relu(z @ w1 + b1)   (h dead after scatter)
    k_gemm_mfma<1><<<gg, 256, 0, stream>>>(z, w1hi, w1hi + 65536,
                                           b1 + (size_t)l * HID, h, Mp);
    // GEMM2: z = h @ w2 + b2
    k_gemm_mfma<0><<<gg, 256, 0, stream>>>(h, w2hi, w2hi + 65536,
                                           b2 + (size_t)l * HID, z, Mp);
    k_bn_stats<<<512, 256, 0, stream>>>(z, stats, n_nodes);
    k_bn_finalize<<<1, 256, 0, stream>>>(stats, gamma + (size_t)l * HID,
                                         beta + (size_t)l * HID, 1.0f / (float)n_nodes);
    k_bn_apply<<<2048, 256, 0, stream>>>(z, stats, h, z, nh / 4);
  }

  k_pool<<<(n_nodes + 31) / 32, 256, 0, stream>>>(h, batch, out, n_nodes, 32);
  k_div<<<n_graphs, 256, 0, stream>>>(out, batch, n_nodes);
}

// Round 5
// 1736.671 us; speedup vs baseline: 3.3115x; 1.3796x over previous
//
#include <hip/hip_runtime.h>

#define HID 256
typedef unsigned short bfb;  // bf16 storage (raw bits)
typedef __attribute__((ext_vector_type(8))) short bf16x8_t;
typedef __attribute__((ext_vector_type(4))) float f32x4_t;

// ---------- bf16 bit helpers (storage-only; math in fp32) ----------
__device__ inline float bfb2f(bfb u) {
  unsigned v = ((unsigned)u) << 16;
  float f;
  __builtin_memcpy(&f, &v, 4);
  return f;
}
__device__ inline bfb f2bfb(float f) {
  unsigned v;
  __builtin_memcpy(&v, &f, 4);
  v += 0x7fff + ((v >> 16) & 1);  // round-to-nearest-even
  return (bfb)(v >> 16);
}
__device__ inline float ldf(const bfb* p, size_t i) { return bfb2f(p[i]); }
__device__ inline void stf(bfb* p, size_t i, float v) { p[i] = f2bfb(v); }
__device__ inline float4 load4f(const bfb* p) {
  ushort4 u = *(const ushort4*)p;
  return make_float4(bfb2f(u.x), bfb2f(u.y), bfb2f(u.z), bfb2f(u.w));
}
__device__ inline void store4f(bfb* p, float4 v) {
  ushort4 u;
  u.x = f2bfb(v.x); u.y = f2bfb(v.y); u.z = f2bfb(v.z); u.w = f2bfb(v.w);
  *(ushort4*)p = u;
}

// async global->LDS, 16B per lane (dest = wave-uniform base + lane*16)
__device__ inline void gld16(const void* g, void* l) {
  __builtin_amdgcn_global_load_lds(
      (const __attribute__((address_space(1))) void*)g,
      (__attribute__((address_space(3))) void*)l, 16, 0, 0);
}

// ---------------- weight prep: Wt_hi[n][k]=bf16(W[k][n]); Wt_lo=bf16(W-hi) ----------------
__global__ __launch_bounds__(256) void k_prep_w(
    const float* __restrict__ w1, const float* __restrict__ w2,
    bfb* __restrict__ wbuf, int n_layers) {
  int t = blockIdx.x * 256 + threadIdx.x;
  int total = n_layers * 2 * 65536;
  if (t >= total) return;
  int l = t / 131072;
  int rem = t - l * 131072;
  int which = rem >> 16;   // 0 = w1, 1 = w2
  int e = rem & 65535;
  int n = e >> 8, k = e & 255;
  const float* src = (which ? w2 : w1) + (size_t)l * 65536;
  float v = src[k * 256 + n];
  bfb hi = f2bfb(v);
  bfb lo = f2bfb(v - bfb2f(hi));
  bfb* dst = wbuf + (size_t)l * 262144 + (size_t)which * 131072;
  dst[e] = hi;
  dst[65536 + e] = lo;
}

// ---------------- input projection: h = x @ in_W + in_b ----------------
__global__ __launch_bounds__(256) void k_input_proj(
    const float* __restrict__ x, const float* __restrict__ W,
    const float* __restrict__ bias, bfb* __restrict__ h, int n_nodes) {
  __shared__ float sW[14 * HID];
  __shared__ float sx[64 * 14];
  for (int i = threadIdx.x; i < 14 * HID; i += blockDim.x) sW[i] = W[i];
  int c = threadIdx.x;
  float b = bias[c];
  int n0 = blockIdx.x * 64;
  int nmax = min(n0 + 64, n_nodes);
  int cnt = (nmax - n0) * 14;
  for (int i = threadIdx.x; i < cnt; i += blockDim.x) sx[i] = x[(size_t)n0 * 14 + i];
  __syncthreads();
  for (int n = n0; n < nmax; n++) {
    const float* xr = &sx[(n - n0) * 14];
    float acc = b;
#pragma unroll
    for (int k = 0; k < 14; k++) acc = fmaf(xr[k], sW[k * HID + c], acc);
    stf(h, (size_t)n * HID + c, acc);
  }
}

// ---------------- CSR build ----------------
__global__ __launch_bounds__(256) void k_hist(const int* __restrict__ dsts,
                                              int* deg, int ne) {
  int e = blockIdx.x * 256 + threadIdx.x;
  if (e < ne) atomicAdd(&deg[dsts[e]], 1);
}

__global__ __launch_bounds__(256) void k_scan1(const int* __restrict__ deg,
                                               int* bsum, int n) {
  __shared__ int sd[256];
  int i0 = blockIdx.x * 1024 + threadIdx.x * 4;
  int s = 0;
#pragma unroll
  for (int j = 0; j < 4; j++) {
    int i = i0 + j;
    if (i < n) s += deg[i];
  }
  sd[threadIdx.x] = s;
  __syncthreads();
  for (int off = 128; off > 0; off >>= 1) {
    if (threadIdx.x < off) sd[threadIdx.x] += sd[threadIdx.x + off];
    __syncthreads();
  }
  if (threadIdx.x == 0) bsum[blockIdx.x] = sd[0];
}

__global__ __launch_bounds__(256) void k_scan2(int* bsum, int nb) {
  __shared__ int sd[256];
  __shared__ int stot;
  int tid = threadIdx.x;
  int carry = 0;
  for (int base = 0; base < nb; base += 256) {
    int v = (base + tid < nb) ? bsum[base + tid] : 0;
    sd[tid] = v;
    __syncthreads();
    for (int off = 1; off < 256; off <<= 1) {
      int t = (tid >= off) ? sd[tid - off] : 0;
      __syncthreads();
      sd[tid] += t;
      __syncthreads();
    }
    int incl = sd[tid];
    if (base + tid < nb) bsum[base + tid] = carry + incl - v;
    if (tid == 255) stot = incl;
    __syncthreads();
    carry += stot;
    __syncthreads();
  }
}

__global__ __launch_bounds__(256) void k_scan3(const int* __restrict__ deg,
                                               const int* __restrict__ bsum,
                                               int* row_start, int* cursor, int n) {
  __shared__ int sd[256];
  int tid = threadIdx.x;
  int i0 = blockIdx.x * 1024 + tid * 4;
  int d[4];
  int s = 0;
#pragma unroll
  for (int j = 0; j < 4; j++) {
    int i = i0 + j;
    d[j] = (i < n) ? deg[i] : 0;
    s += d[j];
  }
  sd[tid] = s;
  __syncthreads();
  for (int off = 1; off < 256; off <<= 1) {
    int t = (tid >= off) ? sd[tid - off] : 0;
    __syncthreads();
    sd[tid] += t;
    __syncthreads();
  }
  int excl = sd[tid] - s + bsum[blockIdx.x];
#pragma unroll
  for (int j = 0; j < 4; j++) {
    int i = i0 + j;
    if (i < n) {
      row_start[i] = excl;
      cursor[i] = excl;
      if (i == n - 1) row_start[n] = excl + d[j];
      excl += d[j];
    }
  }
}

__global__ __launch_bounds__(256) void k_fill(const int* __restrict__ dsts,
                                              int* cursor, int* eids, int ne) {
  int e = blockIdx.x * 256 + threadIdx.x;
  if (e < ne) {
    int p = atomicAdd(&cursor[dsts[e]], 1);
    eids[p] = e;
  }
}

// ---------------- aggregate: z[n] = h[n] + sum_{e: dst=n} relu(h[src]+ea@eW+eb) ----------------
// one wave per node, 4 channels per lane
__global__ __launch_bounds__(256) void k_aggregate(
    const bfb* __restrict__ h, const float* __restrict__ ea,
    const int* __restrict__ srcs, const int* __restrict__ eids,
    const int* __restrict__ row_start, const float* __restrict__ eW,
    const float* __restrict__ eb, bfb* __restrict__ z, int n_nodes) {
  __shared__ float sw0[HID], sw1[HID], sw2[HID], sb[HID];
  int tid = threadIdx.x;
  sw0[tid] = eW[tid];
  sw1[tid] = eW[HID + tid];
  sw2[tid] = eW[2 * HID + tid];
  sb[tid] = eb[tid];
  __syncthreads();
  int w = tid >> 6, lane = tid & 63;
  int n = blockIdx.x * 4 + w;
  if (n >= n_nodes) return;
  int c0 = lane * 4;
  float w0[4], w1[4], w2[4], bb[4];
#pragma unroll
  for (int j = 0; j < 4; j++) {
    w0[j] = sw0[c0 + j]; w1[j] = sw1[c0 + j]; w2[j] = sw2[c0 + j]; bb[j] = sb[c0 + j];
  }
  ushort4 hv = *(const ushort4*)&h[(size_t)n * HID + c0];
  float acc[4] = {bfb2f(hv.x), bfb2f(hv.y), bfb2f(hv.z), bfb2f(hv.w)};
  int i0 = row_start[n], i1 = row_start[n + 1];
  for (int i = i0; i < i1; i++) {
    int e = eids[i];
    int s = srcs[e];
    float a0 = ea[(size_t)e * 3], a1 = ea[(size_t)e * 3 + 1], a2 = ea[(size_t)e * 3 + 2];
    ushort4 sv = *(const ushort4*)&h[(size_t)s * HID + c0];
    float hs[4] = {bfb2f(sv.x), bfb2f(sv.y), bfb2f(sv.z), bfb2f(sv.w)};
#pragma unroll
    for (int j = 0; j < 4; j++) {
      float m = hs[j] + fmaf(a0, w0[j], fmaf(a1, w1[j], fmaf(a2, w2[j], bb[j])));
      acc[j] += fmaxf(m, 0.0f);
    }
  }
  ushort4 o;
  o.x = f2bfb(acc[0]); o.y = f2bfb(acc[1]); o.z = f2bfb(acc[2]); o.w = f2bfb(acc[3]);
  *(ushort4*)&z[(size_t)n * HID + c0] = o;
}

// ---------------- MFMA GEMM: C = (relu?)(A @ (Whi+Wlo)^T' + bias); optional fused BN stats ----------------
template <int RELU, int STATS>
__global__ __launch_bounds__(256) void k_gemm_mfma(
    const bfb* __restrict__ A, const bfb* __restrict__ Whi,
    const bfb* __restrict__ Wlo, const float* __restrict__ bias,
    bfb* __restrict__ C, int Mp, int Mreal, float* stats) {
  __shared__ __align__(16) bfb As[8192];  // [128 rows][64 k] swizzled, 16KB
  __shared__ __align__(16) bfb Bh[8192];
  __shared__ __align__(16) bfb Bl[8192];
  int tid = threadIdx.x;
  int lane = tid & 63, wid = tid >> 6;
  int wr = wid >> 1, wc = wid & 1;
  size_t bm = (size_t)blockIdx.x * 128;
  int n0 = blockIdx.y * 128;

  int srow = tid >> 3;
  int sel = (((tid & 7) * 16) ^ ((srow & 7) << 4)) >> 1;
  int ldst = wid * 512;

  f32x4_t acc[4][4] = {};

  int sw = (lane & 7) << 4;
  int arow = wr * 64 + (lane & 15);
  int brow = wc * 64 + (lane & 15);
  int kgb = (lane >> 4) * 16;

  for (int kt = 0; kt < 4; kt++) {
    int k0 = kt * 64;
    const bfb* abase = A + bm * 256 + k0 + sel;
    const bfb* hbase = Whi + (size_t)n0 * 256 + k0 + sel;
    const bfb* lbase = Wlo + (size_t)n0 * 256 + k0 + sel;
#pragma unroll
    for (int i = 0; i < 4; i++) {
      gld16(abase + (size_t)(i * 32 + srow) * 256, As + i * 2048 + ldst);
      gld16(hbase + (size_t)(i * 32 + srow) * 256, Bh + i * 2048 + ldst);
      gld16(lbase + (size_t)(i * 32 + srow) * 256, Bl + i * 2048 + ldst);
    }
    __syncthreads();
#pragma unroll
    for (int ks = 0; ks < 2; ks++) {
      int kb = ks * 64 + kgb;
      bf16x8_t af[4], bh[4], bl[4];
#pragma unroll
      for (int mi = 0; mi < 4; mi++) {
        int pb = (arow + mi * 16) * 128 + (kb ^ sw);
        af[mi] = *(const bf16x8_t*)((const char*)As + pb);
      }
#pragma unroll
      for (int ni = 0; ni < 4; ni++) {
        int pb = (brow + ni * 16) * 128 + (kb ^ sw);
        bh[ni] = *(const bf16x8_t*)((const char*)Bh + pb);
        bl[ni] = *(const bf16x8_t*)((const char*)Bl + pb);
      }
#pragma unroll
      for (int mi = 0; mi < 4; mi++)
#pragma unroll
        for (int ni = 0; ni < 4; ni++) {
          acc[mi][ni] = __builtin_amdgcn_mfma_f32_16x16x32_bf16(
              af[mi], bh[ni], acc[mi][ni], 0, 0, 0);
          acc[mi][ni] = __builtin_amdgcn_mfma_f32_16x16x32_bf16(
              af[mi], bl[ni], acc[mi][ni], 0, 0, 0);
        }
    }
    __syncthreads();
  }
  // epilogue: C/D layout col=lane&15, row=(lane>>4)*4+reg
  int crow0 = wr * 64 + (lane >> 4) * 4;
  int ccol0 = n0 + wc * 64 + (lane & 15);
  float ssum[4] = {}, ssq[4] = {};
#pragma unroll
  for (int ni = 0; ni < 4; ni++) {
    float b = bias[ccol0 + ni * 16];
#pragma unroll
    for (int mi = 0; mi < 4; mi++) {
#pragma unroll
      for (int r = 0; r < 4; r++) {
        int grow = (int)bm + crow0 + mi * 16 + r;
        float v = acc[mi][ni][r] + b;
        if (RELU) v = fmaxf(v, 0.0f);
        C[(size_t)grow * 256 + ccol0 + ni * 16] = f2bfb(v);
        if (STATS && grow < Mreal) {
          ssum[ni] += v;
          ssq[ni] = fmaf(v, v, ssq[ni]);
        }
      }
    }
  }
  if (STATS) {
#pragma unroll
    for (int ni = 0; ni < 4; ni++) {
      float s = ssum[ni], q = ssq[ni];
      s += __shfl_xor(s, 16); s += __shfl_xor(s, 32);
      q += __shfl_xor(q, 16); q += __shfl_xor(q, 32);
      if ((lane >> 4) == 0) {
        atomicAdd(&stats[ccol0 + ni * 16], s);
        atomicAdd(&stats[HID + ccol0 + ni * 16], q);
      }
    }
  }
}

// ---------------- BN finalize ----------------
__global__ __launch_bounds__(256) void k_bn_finalize(
    float* stats, const float* __restrict__ gamma, const float* __restrict__ beta,
    float inv_n) {
  int c = threadIdx.x;
  float mu = stats[c] * inv_n;
  float var = stats[HID + c] * inv_n - mu * mu;
  float sc = gamma[c] * rsqrtf(var + 1e-5f);
  stats[2 * HID + c] = sc;
  stats[3 * HID + c] = beta[c] - mu * sc;
}

// ---------------- BN apply + relu -> h ----------------
__global__ __launch_bounds__(256) void k_bn_apply(
    const bfb* zin, const float* __restrict__ stats, bfb* h, size_t total4) {
  __shared__ float ssc[HID], ssh[HID];
  ssc[threadIdx.x] = stats[2 * HID + threadIdx.x];
  ssh[threadIdx.x] = stats[3 * HID + threadIdx.x];
  __syncthreads();
  size_t stride = (size_t)gridDim.x * blockDim.x;
  for (size_t i = (size_t)blockIdx.x * blockDim.x + threadIdx.x; i < total4; i += stride) {
    float4 v = load4f(zin + i * 4);
    int c = (int)((i * 4) & (HID - 1));
    v.x = fmaxf(fmaf(v.x, ssc[c + 0], ssh[c + 0]), 0.0f);
    v.y = fmaxf(fmaf(v.y, ssc[c + 1], ssh[c + 1]), 0.0f);
    v.z = fmaxf(fmaf(v.z, ssc[c + 2], ssh[c + 2]), 0.0f);
    v.w = fmaxf(fmaf(v.w, ssc[c + 3], ssh[c + 3]), 0.0f);
    store4f(h + i * 4, v);
  }
}

// ---------------- pool + divide ----------------
__global__ __launch_bounds__(256) void k_pool(
    const bfb* __restrict__ h, const int* __restrict__ batch,
    float* out, int n_nodes, int npb) {
  int c = threadIdx.x;
  int n0 = blockIdx.x * npb;
  int n1 = min(n0 + npb, n_nodes);
  if (n0 >= n1) return;
  int cur = batch[n0];
  float acc = 0.0f;
  for (int n = n0; n < n1; n++) {
    int g = batch[n];
    if (g != cur) {
      atomicAdd(&out[(size_t)cur * HID + c], acc);
      acc = 0.0f;
      cur = g;
    }
    acc += ldf(h, (size_t)n * HID + c);
  }
  atomicAdd(&out[(size_t)cur * HID + c], acc);
}

__global__ __launch_bounds__(256) void k_div(
    float* out, const int* __restrict__ batch, int n_nodes) {
  int g = blockIdx.x;
  int lo = 0, hi = n_nodes;
  while (lo < hi) {
    int mid = (lo + hi) >> 1;
    if (batch[mid] < g) lo = mid + 1; else hi = mid;
  }
  int lo2 = lo, hi2 = n_nodes;
  while (lo2 < hi2) {
    int mid = (lo2 + hi2) >> 1;
    if (batch[mid] < g + 1) lo2 = mid + 1; else hi2 = mid;
  }
  float cnt = (float)(lo2 - lo);
  float inv = 1.0f / fmaxf(cnt, 1.0f);
  out[(size_t)g * HID + threadIdx.x] *= inv;
}

extern "C" void kernel_launch(void* const* d_in, const int* in_sizes, int n_in,
                              void* d_out, int out_size, void* d_ws, size_t ws_size,
                              hipStream_t stream) {
  const float* x = (const float*)d_in[0];
  const float* edge_attr = (const float*)d_in[1];
  const int* edge_index = (const int*)d_in[2];
  const int* batch = (const int*)d_in[3];
  const float* in_W = (const float*)d_in[4];
  const float* in_b = (const float*)d_in[5];
  const float* edge_W = (const float*)d_in[6];
  const float* edge_b = (const float*)d_in[7];
  const float* w1 = (const float*)d_in[8];
  const float* b1 = (const float*)d_in[9];
  const float* w2 = (const float*)d_in[10];
  const float* b2 = (const float*)d_in[11];
  const float* gamma = (const float*)d_in[12];
  const float* beta = (const float*)d_in[13];
  float* out = (float*)d_out;

  int n_nodes = in_sizes[3];
  int n_edges = in_sizes[1] / 3;
  int n_graphs = out_size / HID;
  int n_layers = in_sizes[7] / HID;

  const int* srcs = edge_index;
  const int* dsts = edge_index + n_edges;

  int Mp = ((n_nodes + 127) / 128) * 128;
  size_t nh = (size_t)n_nodes * HID;
  size_t nhp = (size_t)Mp * HID;

  // ws layout: stats | wbuf | deg | row_start | cursor | eids | bsum | h | z
  char* ws = (char*)d_ws;
  size_t off = 0;
  float* stats = (float*)(ws + off); off += 4096;
  bfb* wbuf = (bfb*)(ws + off); off += (size_t)n_layers * 262144 * 2;
  int* deg = (int*)(ws + off); off += ((size_t)n_nodes * 4 + 15) & ~15ull;
  int* row_start = (int*)(ws + off); off += ((size_t)(n_nodes + 1) * 4 + 15) & ~15ull;
  int* cursor = (int*)(ws + off); off += ((size_t)n_nodes * 4 + 15) & ~15ull;
  int* eids = (int*)(ws + off); off += ((size_t)n_edges * 4 + 15) & ~15ull;
  int* bsum = (int*)(ws + off); off += 4096;
  bfb* h = (bfb*)(ws + off); off += nhp * 2;
  bfb* z = (bfb*)(ws + off);

  hipMemsetAsync(out, 0, (size_t)out_size * sizeof(float), stream);
  hipMemsetAsync(deg, 0, (size_t)n_nodes * 4, stream);

  k_prep_w<<<(n_layers * 131072 + 255) / 256, 256, 0, stream>>>(w1, w2, wbuf, n_layers);
  k_input_proj<<<(n_nodes + 63) / 64, 256, 0, stream>>>(x, in_W, in_b, h, n_nodes);

  // CSR build (once; edge_index is layer-invariant)
  int np = (n_nodes + 1023) / 1024;
  k_hist<<<(n_edges + 255) / 256, 256, 0, stream>>>(dsts, deg, n_edges);
  k_scan1<<<np, 256, 0, stream>>>(deg, bsum, n_nodes);
  k_scan2<<<1, 256, 0, stream>>>(bsum, np);
  k_scan3<<<np, 256, 0, stream>>>(deg, bsum, row_start, cursor, n_nodes);
  k_fill<<<(n_edges + 255) / 256, 256, 0, stream>>>(dsts, cursor, eids, n_edges);

  dim3 gg(Mp / 128, 2);
  for (int l = 0; l < n_layers; l++) {
    hipMemsetAsync(stats, 0, 2 * HID * sizeof(float), stream);
    k_aggregate<<<(n_nodes + 3) / 4, 256, 0, stream>>>(
        h, edge_attr, srcs, eids, row_start,
        edge_W + (size_t)l * 3 * HID, edge_b + (size_t)l * HID, z, n_nodes);
    bfb* w1hi = wbuf + (size_t)l * 262144;
    bfb* w2hi = w1hi + 131072;
    // GEMM1: h = relu(z @ w1 + b1)
    k_gemm_mfma<1, 0><<<gg, 256, 0, stream>>>(z, w1hi, w1hi + 65536,
                                              b1 + (size_t)l * HID, h, Mp,
                                              n_nodes, nullptr);
    // GEMM2: z = h @ w2 + b2, fused BN stats
    k_gemm_mfma<0, 1><<<gg, 256, 0, stream>>>(h, w2hi, w2hi + 65536,
                                              b2 + (size_t)l * HID, z, Mp,
                                              n_nodes, stats);
    k_bn_finalize<<<1, 256, 0, stream>>>(stats, gamma + (size_t)l * HID,
                                         beta + (size_t)l * HID, 1.0f / (float)n_nodes);
    k_bn_apply<<<2048, 256, 0, stream>>>(z, stats, h, nh / 4);
  }

  k_pool<<<(n_nodes + 31) / 32, 256, 0, stream>>>(h, batch, out, n_nodes, 32);
  k_div<<<n_graphs, 256, 0, stream>>>(out, batch, n_nodes);
}

// Round 6
// 1279.557 us; speedup vs baseline: 4.4946x; 1.3572x over previous
//
#include <hip/hip_runtime.h>

#define HID 256
typedef unsigned short bfb;  // bf16 storage (raw bits)
typedef __attribute__((ext_vector_type(8))) short bf16x8_t;
typedef __attribute__((ext_vector_type(4))) float f32x4_t;

// ---------- bf16 bit helpers (storage-only; math in fp32) ----------
__device__ inline float bfb2f(bfb u) {
  unsigned v = ((unsigned)u) << 16;
  float f;
  __builtin_memcpy(&f, &v, 4);
  return f;
}
__device__ inline bfb f2bfb(float f) {
  unsigned v;
  __builtin_memcpy(&v, &f, 4);
  v += 0x7fff + ((v >> 16) & 1);  // round-to-nearest-even
  return (bfb)(v >> 16);
}
__device__ inline float ldf(const bfb* p, size_t i) { return bfb2f(p[i]); }
__device__ inline void stf(bfb* p, size_t i, float v) { p[i] = f2bfb(v); }

// async global->LDS, 16B per lane (dest = wave-uniform base + lane*16)
__device__ inline void gld16(const void* g, void* l) {
  __builtin_amdgcn_global_load_lds(
      (const __attribute__((address_space(1))) void*)g,
      (__attribute__((address_space(3))) void*)l, 16, 0, 0);
}

// ---------------- weight prep: Wt_hi[n][k]=bf16(W[k][n]); Wt_lo=bf16(W-hi) ----------------
__global__ __launch_bounds__(256) void k_prep_w(
    const float* __restrict__ w1, const float* __restrict__ w2,
    bfb* __restrict__ wbuf, int n_layers) {
  int t = blockIdx.x * 256 + threadIdx.x;
  int total = n_layers * 2 * 65536;
  if (t >= total) return;
  int l = t / 131072;
  int rem = t - l * 131072;
  int which = rem >> 16;   // 0 = w1, 1 = w2
  int e = rem & 65535;
  int n = e >> 8, k = e & 255;
  const float* src = (which ? w2 : w1) + (size_t)l * 65536;
  float v = src[k * 256 + n];
  bfb hi = f2bfb(v);
  bfb lo = f2bfb(v - bfb2f(hi));
  bfb* dst = wbuf + (size_t)l * 262144 + (size_t)which * 131072;
  dst[e] = hi;
  dst[65536 + e] = lo;
}

// ---------------- input projection: z0 = x @ in_W + in_b (raw, no relu) ----------------
__global__ __launch_bounds__(256) void k_input_proj(
    const float* __restrict__ x, const float* __restrict__ W,
    const float* __restrict__ bias, bfb* __restrict__ z, int n_nodes) {
  __shared__ float sW[14 * HID];
  __shared__ float sx[64 * 14];
  for (int i = threadIdx.x; i < 14 * HID; i += blockDim.x) sW[i] = W[i];
  int c = threadIdx.x;
  float b = bias[c];
  int n0 = blockIdx.x * 64;
  int nmax = min(n0 + 64, n_nodes);
  int cnt = (nmax - n0) * 14;
  for (int i = threadIdx.x; i < cnt; i += blockDim.x) sx[i] = x[(size_t)n0 * 14 + i];
  __syncthreads();
  for (int n = n0; n < nmax; n++) {
    const float* xr = &sx[(n - n0) * 14];
    float acc = b;
#pragma unroll
    for (int k = 0; k < 14; k++) acc = fmaf(xr[k], sW[k * HID + c], acc);
    stf(z, (size_t)n * HID + c, acc);
  }
}

// ---------------- CSR build ----------------
__global__ __launch_bounds__(256) void k_hist(const int* __restrict__ dsts,
                                              int* deg, int ne) {
  int e = blockIdx.x * 256 + threadIdx.x;
  if (e < ne) atomicAdd(&deg[dsts[e]], 1);
}

__global__ __launch_bounds__(256) void k_scan1(const int* __restrict__ deg,
                                               int* bsum, int n) {
  __shared__ int sd[256];
  int i0 = blockIdx.x * 1024 + threadIdx.x * 4;
  int s = 0;
#pragma unroll
  for (int j = 0; j < 4; j++) {
    int i = i0 + j;
    if (i < n) s += deg[i];
  }
  sd[threadIdx.x] = s;
  __syncthreads();
  for (int off = 128; off > 0; off >>= 1) {
    if (threadIdx.x < off) sd[threadIdx.x] += sd[threadIdx.x + off];
    __syncthreads();
  }
  if (threadIdx.x == 0) bsum[blockIdx.x] = sd[0];
}

__global__ __launch_bounds__(256) void k_scan2(int* bsum, int nb) {
  __shared__ int sd[256];
  __shared__ int stot;
  int tid = threadIdx.x;
  int carry = 0;
  for (int base = 0; base < nb; base += 256) {
    int v = (base + tid < nb) ? bsum[base + tid] : 0;
    sd[tid] = v;
    __syncthreads();
    for (int off = 1; off < 256; off <<= 1) {
      int t = (tid >= off) ? sd[tid - off] : 0;
      __syncthreads();
      sd[tid] += t;
      __syncthreads();
    }
    int incl = sd[tid];
    if (base + tid < nb) bsum[base + tid] = carry + incl - v;
    if (tid == 255) stot = incl;
    __syncthreads();
    carry += stot;
    __syncthreads();
  }
}

__global__ __launch_bounds__(256) void k_scan3(const int* __restrict__ deg,
                                               const int* __restrict__ bsum,
                                               int* row_start, int* cursor, int n) {
  __shared__ int sd[256];
  int tid = threadIdx.x;
  int i0 = blockIdx.x * 1024 + tid * 4;
  int d[4];
  int s = 0;
#pragma unroll
  for (int j = 0; j < 4; j++) {
    int i = i0 + j;
    d[j] = (i < n) ? deg[i] : 0;
    s += d[j];
  }
  sd[tid] = s;
  __syncthreads();
  for (int off = 1; off < 256; off <<= 1) {
    int t = (tid >= off) ? sd[tid - off] : 0;
    __syncthreads();
    sd[tid] += t;
    __syncthreads();
  }
  int excl = sd[tid] - s + bsum[blockIdx.x];
#pragma unroll
  for (int j = 0; j < 4; j++) {
    int i = i0 + j;
    if (i < n) {
      row_start[i] = excl;
      cursor[i] = excl;
      if (i == n - 1) row_start[n] = excl + d[j];
      excl += d[j];
    }
  }
}

__global__ __launch_bounds__(256) void k_fill(const int* __restrict__ dsts,
                                              int* cursor, int* eids, int ne) {
  int e = blockIdx.x * 256 + threadIdx.x;
  if (e < ne) {
    int p = atomicAdd(&cursor[dsts[e]], 1);
    eids[p] = e;
  }
}

// ---- set identity BN params for layer 0 (sc=1, sh=0) ----
__global__ __launch_bounds__(256) void k_set_ident(float* stats) {
  stats[2 * HID + threadIdx.x] = 1.0f;
  stats[3 * HID + threadIdx.x] = 0.0f;
}

// ---------------- aggregate with on-the-fly BN+relu ----------------
// h(n) = BN? max(sc*z+sh,0) : z ;  zout[n] = h(n) + sum_e relu(h(src)+ea@eW+eb)
template <int BN>
__global__ __launch_bounds__(256) void k_aggregate(
    const bfb* __restrict__ zin, const float* __restrict__ ea,
    const int* __restrict__ srcs, const int* __restrict__ eids,
    const int* __restrict__ row_start, const float* __restrict__ eW,
    const float* __restrict__ eb, const float* __restrict__ stats,
    bfb* __restrict__ zout, int n_nodes) {
  __shared__ float sw0[HID], sw1[HID], sw2[HID], sb[HID], ssc[HID], ssh[HID];
  int tid = threadIdx.x;
  sw0[tid] = eW[tid];
  sw1[tid] = eW[HID + tid];
  sw2[tid] = eW[2 * HID + tid];
  sb[tid] = eb[tid];
  if (BN) {
    ssc[tid] = stats[2 * HID + tid];
    ssh[tid] = stats[3 * HID + tid];
  }
  __syncthreads();
  int w = tid >> 6, lane = tid & 63;
  int n = blockIdx.x * 4 + w;
  if (n >= n_nodes) return;
  int c0 = lane * 4;
  float w0[4], w1[4], w2[4], bb[4], sc[4], sh[4];
#pragma unroll
  for (int j = 0; j < 4; j++) {
    w0[j] = sw0[c0 + j]; w1[j] = sw1[c0 + j]; w2[j] = sw2[c0 + j]; bb[j] = sb[c0 + j];
    if (BN) { sc[j] = ssc[c0 + j]; sh[j] = ssh[c0 + j]; }
  }
  ushort4 hv = *(const ushort4*)&zin[(size_t)n * HID + c0];
  float hvf[4] = {bfb2f(hv.x), bfb2f(hv.y), bfb2f(hv.z), bfb2f(hv.w)};
  float acc[4];
#pragma unroll
  for (int j = 0; j < 4; j++)
    acc[j] = BN ? fmaxf(fmaf(hvf[j], sc[j], sh[j]), 0.0f) : hvf[j];
  int i0 = row_start[n], i1 = row_start[n + 1];
  for (int i = i0; i < i1; i++) {
    int e = eids[i];
    int s = srcs[e];
    float a0 = ea[(size_t)e * 3], a1 = ea[(size_t)e * 3 + 1], a2 = ea[(size_t)e * 3 + 2];
    ushort4 sv = *(const ushort4*)&zin[(size_t)s * HID + c0];
    float hs[4] = {bfb2f(sv.x), bfb2f(sv.y), bfb2f(sv.z), bfb2f(sv.w)};
#pragma unroll
    for (int j = 0; j < 4; j++) {
      float hsj = BN ? fmaxf(fmaf(hs[j], sc[j], sh[j]), 0.0f) : hs[j];
      float m = hsj + fmaf(a0, w0[j], fmaf(a1, w1[j], fmaf(a2, w2[j], bb[j])));
      acc[j] += fmaxf(m, 0.0f);
    }
  }
  ushort4 o;
  o.x = f2bfb(acc[0]); o.y = f2bfb(acc[1]); o.z = f2bfb(acc[2]); o.w = f2bfb(acc[3]);
  *(ushort4*)&zout[(size_t)n * HID + c0] = o;
}

// ---------------- MFMA GEMM v2: C[Mp][256] = (relu?)(A @ (Whi+Wlo)^T' + bias) ----------------
// 128x256 tile, 512 threads (8 waves 2x4), BK=64, LDS-bounce coalesced epilogue.
template <int RELU, int STATS>
__global__ __launch_bounds__(512, 4) void k_gemm_mfma(
    const bfb* __restrict__ A, const bfb* __restrict__ Whi,
    const bfb* __restrict__ Wlo, const float* __restrict__ bias,
    bfb* __restrict__ C, int Mreal, float* __restrict__ stats) {
  __shared__ __align__(16) bfb smem[40960];  // 80 KB
  bfb* As = smem;           // [128][64] swizzled (16 KB)
  bfb* Bh = smem + 8192;    // [256][64] swizzled (32 KB)
  bfb* Bl = smem + 24576;   // [256][64] swizzled (32 KB)
  int tid = threadIdx.x;
  int lane = tid & 63, wid = tid >> 6;
  int wrow = wid >> 2, wcol = wid & 3;
  size_t bm = (size_t)blockIdx.x * 128;

  int srow = tid >> 3;                                     // 0..63 row in 64-row chunk
  int sel = (((tid & 7) * 16) ^ ((srow & 7) << 4)) >> 1;   // pre-swizzled source col
  int ldst = wid * 512;                                    // wave-uniform dest (elems)

  f32x4_t acc[4][4] = {};
  int sw = (lane & 7) << 4;
  int arow = wrow * 64 + (lane & 15);
  int brow = wcol * 64 + (lane & 15);
  int kgb = (lane >> 4) * 16;

  for (int kt = 0; kt < 4; kt++) {
    int k0 = kt * 64;
    const bfb* ab = A + bm * 256 + k0 + sel;
    const bfb* hb = Whi + k0 + sel;
    const bfb* lb = Wlo + k0 + sel;
#pragma unroll
    for (int i = 0; i < 2; i++)
      gld16(ab + (size_t)(i * 64 + srow) * 256, As + i * 4096 + ldst);
#pragma unroll
    for (int i = 0; i < 4; i++) {
      gld16(hb + (size_t)(i * 64 + srow) * 256, Bh + i * 4096 + ldst);
      gld16(lb + (size_t)(i * 64 + srow) * 256, Bl + i * 4096 + ldst);
    }
    __syncthreads();
#pragma unroll
    for (int ks = 0; ks < 2; ks++) {
      int kb = ks * 64 + kgb;
      bf16x8_t af[4];
#pragma unroll
      for (int mi = 0; mi < 4; mi++)
        af[mi] = *(const bf16x8_t*)((const char*)As + (arow + mi * 16) * 128 + (kb ^ sw));
#pragma unroll
      for (int ni = 0; ni < 4; ni++) {
        int pb = (brow + ni * 16) * 128 + (kb ^ sw);
        bf16x8_t bh = *(const bf16x8_t*)((const char*)Bh + pb);
        bf16x8_t bl = *(const bf16x8_t*)((const char*)Bl + pb);
#pragma unroll
        for (int mi = 0; mi < 4; mi++) {
          acc[mi][ni] = __builtin_amdgcn_mfma_f32_16x16x32_bf16(af[mi], bh, acc[mi][ni], 0, 0, 0);
          acc[mi][ni] = __builtin_amdgcn_mfma_f32_16x16x32_bf16(af[mi], bl, acc[mi][ni], 0, 0, 0);
        }
      }
    }
    __syncthreads();
  }
  // epilogue: bias(+relu)(+stats) -> LDS bounce -> coalesced float4 stores
  bfb* Cs = smem + 8192;  // [128][256] bf16 = 64 KB (reuses Bh+Bl)
  int crow0 = wrow * 64 + (lane >> 4) * 4;
  int ccol0 = wcol * 64 + (lane & 15);
  float ssum[4] = {}, ssq[4] = {};
#pragma unroll
  for (int ni = 0; ni < 4; ni++) {
    float b = bias[ccol0 + ni * 16];
#pragma unroll
    for (int mi = 0; mi < 4; mi++) {
#pragma unroll
      for (int r = 0; r < 4; r++) {
        int row = crow0 + mi * 16 + r;
        float v = acc[mi][ni][r] + b;
        if (RELU) v = fmaxf(v, 0.0f);
        Cs[row * 256 + ccol0 + ni * 16] = f2bfb(v);
        if (STATS && (int)bm + row < Mreal) {
          ssum[ni] += v;
          ssq[ni] = fmaf(v, v, ssq[ni]);
        }
      }
    }
  }
  if (STATS) {
#pragma unroll
    for (int ni = 0; ni < 4; ni++) {
      float s = ssum[ni], q = ssq[ni];
      s += __shfl_xor(s, 16); s += __shfl_xor(s, 32);
      q += __shfl_xor(q, 16); q += __shfl_xor(q, 32);
      if ((lane >> 4) == 0) {
        atomicAdd(&stats[ccol0 + ni * 16], s);
        atomicAdd(&stats[HID + ccol0 + ni * 16], q);
      }
    }
  }
  __syncthreads();
  bfb* Cg = C + bm * 256;
#pragma unroll
  for (int j = 0; j < 8; j++) {
    int idx = j * 4096 + tid * 8;
    *(float4*)(Cg + idx) = *(const float4*)(Cs + idx);
  }
}

// ---------------- BN finalize ----------------
__global__ __launch_bounds__(256) void k_bn_finalize(
    float* stats, const float* __restrict__ gamma, const float* __restrict__ beta,
    float inv_n) {
  int c = threadIdx.x;
  float mu = stats[c] * inv_n;
  float var = stats[HID + c] * inv_n - mu * mu;
  float sc = gamma[c] * rsqrtf(var + 1e-5f);
  stats[2 * HID + c] = sc;
  stats[3 * HID + c] = beta[c] - mu * sc;
}

// ---------------- pool (BN+relu on the fly) + divide ----------------
__global__ __launch_bounds__(256) void k_pool(
    const bfb* __restrict__ z, const float* __restrict__ stats,
    const int* __restrict__ batch, float* out, int n_nodes, int npb) {
  int c = threadIdx.x;
  float sc = stats[2 * HID + c];
  float sh = stats[3 * HID + c];
  int n0 = blockIdx.x * npb;
  int n1 = min(n0 + npb, n_nodes);
  if (n0 >= n1) return;
  int cur = batch[n0];
  float acc = 0.0f;
  for (int n = n0; n < n1; n++) {
    int g = batch[n];
    if (g != cur) {
      atomicAdd(&out[(size_t)cur * HID + c], acc);
      acc = 0.0f;
      cur = g;
    }
    acc += fmaxf(fmaf(ldf(z, (size_t)n * HID + c), sc, sh), 0.0f);
  }
  atomicAdd(&out[(size_t)cur * HID + c], acc);
}

__global__ __launch_bounds__(256) void k_div(
    float* out, const int* __restrict__ batch, int n_nodes) {
  int g = blockIdx.x;
  int lo = 0, hi = n_nodes;
  while (lo < hi) {
    int mid = (lo + hi) >> 1;
    if (batch[mid] < g) lo = mid + 1; else hi = mid;
  }
  int lo2 = lo, hi2 = n_nodes;
  while (lo2 < hi2) {
    int mid = (lo2 + hi2) >> 1;
    if (batch[mid] < g + 1) lo2 = mid + 1; else hi2 = mid;
  }
  float cnt = (float)(lo2 - lo);
  float inv = 1.0f / fmaxf(cnt, 1.0f);
  out[(size_t)g * HID + threadIdx.x] *= inv;
}

extern "C" void kernel_launch(void* const* d_in, const int* in_sizes, int n_in,
                              void* d_out, int out_size, void* d_ws, size_t ws_size,
                              hipStream_t stream) {
  const float* x = (const float*)d_in[0];
  const float* edge_attr = (const float*)d_in[1];
  const int* edge_index = (const int*)d_in[2];
  const int* batch = (const int*)d_in[3];
  const float* in_W = (const float*)d_in[4];
  const float* in_b = (const float*)d_in[5];
  const float* edge_W = (const float*)d_in[6];
  const float* edge_b = (const float*)d_in[7];
  const float* w1 = (const float*)d_in[8];
  const float* b1 = (const float*)d_in[9];
  const float* w2 = (const float*)d_in[10];
  const float* b2 = (const float*)d_in[11];
  const float* gamma = (const float*)d_in[12];
  const float* beta = (const float*)d_in[13];
  float* out = (float*)d_out;

  int n_nodes = in_sizes[3];
  int n_edges = in_sizes[1] / 3;
  int n_graphs = out_size / HID;
  int n_layers = in_sizes[7] / HID;

  const int* srcs = edge_index;
  const int* dsts = edge_index + n_edges;

  int Mp = ((n_nodes + 127) / 128) * 128;
  size_t nhp = (size_t)Mp * HID;

  // ws layout: stats | wbuf | deg | row_start | cursor | eids | bsum | P0 | P1
  char* ws = (char*)d_ws;
  size_t off = 0;
  float* stats = (float*)(ws + off); off += 4096;
  bfb* wbuf = (bfb*)(ws + off); off += (size_t)n_layers * 262144 * 2;
  int* deg = (int*)(ws + off); off += ((size_t)n_nodes * 4 + 255) & ~255ull;
  int* row_start = (int*)(ws + off); off += ((size_t)(n_nodes + 1) * 4 + 255) & ~255ull;
  int* cursor = (int*)(ws + off); off += ((size_t)n_nodes * 4 + 255) & ~255ull;
  int* eids = (int*)(ws + off); off += ((size_t)n_edges * 4 + 255) & ~255ull;
  int* bsum = (int*)(ws + off); off += 4096;
  bfb* P0 = (bfb*)(ws + off); off += nhp * 2;
  bfb* P1 = (bfb*)(ws + off);

  hipMemsetAsync(out, 0, (size_t)out_size * sizeof(float), stream);
  hipMemsetAsync(deg, 0, (size_t)n_nodes * 4, stream);

  k_prep_w<<<(n_layers * 131072 + 255) / 256, 256, 0, stream>>>(w1, w2, wbuf, n_layers);
  k_input_proj<<<(n_nodes + 63) / 64, 256, 0, stream>>>(x, in_W, in_b, P0, n_nodes);

  // CSR build (once; edge_index is layer-invariant)
  int np = (n_nodes + 1023) / 1024;
  k_hist<<<(n_edges + 255) / 256, 256, 0, stream>>>(dsts, deg, n_edges);
  k_scan1<<<np, 256, 0, stream>>>(deg, bsum, n_nodes);
  k_scan2<<<1, 256, 0, stream>>>(bsum, np);
  k_scan3<<<np, 256, 0, stream>>>(deg, bsum, row_start, cursor, n_nodes);
  k_fill<<<(n_edges + 255) / 256, 256, 0, stream>>>(dsts, cursor, eids, n_edges);

  bfb* cur = P0;  // layer input (raw pre-BN activations)
  bfb* oth = P1;
  int gagg = (n_nodes + 3) / 4;
  for (int l = 0; l < n_layers; l++) {
    // aggregate: oth = h(cur) + scatter(relu(h(src)+emsg)), h = BNrelu except layer 0
    if (l == 0)
      k_aggregate<0><<<gagg, 256, 0, stream>>>(
          cur, edge_attr, srcs, eids, row_start,
          edge_W + (size_t)l * 3 * HID, edge_b + (size_t)l * HID, stats, oth, n_nodes);
    else
      k_aggregate<1><<<gagg, 256, 0, stream>>>(
          cur, edge_attr, srcs, eids, row_start,
          edge_W + (size_t)l * 3 * HID, edge_b + (size_t)l * HID, stats, oth, n_nodes);
    hipMemsetAsync(stats, 0, 2 * HID * sizeof(float), stream);  // sums only
    bfb* w1hi = wbuf + (size_t)l * 262144;
    bfb* w2hi = w1hi + 131072;
    // GEMM1: cur = relu(oth @ w1 + b1)
    k_gemm_mfma<1, 0><<<Mp / 128, 512, 0, stream>>>(
        oth, w1hi, w1hi + 65536, b1 + (size_t)l * HID, cur, n_nodes, nullptr);
    // GEMM2: oth = cur @ w2 + b2  (+ fused BN sums)
    k_gemm_mfma<0, 1><<<Mp / 128, 512, 0, stream>>>(
        cur, w2hi, w2hi + 65536, b2 + (size_t)l * HID, oth, n_nodes, stats);
    k_bn_finalize<<<1, 256, 0, stream>>>(stats, gamma + (size_t)l * HID,
                                         beta + (size_t)l * HID, 1.0f / (float)n_nodes);
    bfb* t = cur; cur = oth; oth = t;  // cur now holds this layer's raw z
  }

  k_pool<<<(n_nodes + 31) / 32, 256, 0, stream>>>(cur, stats, batch, out, n_nodes, 32);
  k_div<<<n_graphs, 256, 0, stream>>>(out, batch, n_nodes);
}